// Round 11
// baseline (2199.057 us; speedup 1.0000x reference)
//
#include <hip/hip_runtime.h>
#include <math.h>

#define T_ 512
#define N_ 64
#define E_ 1024
#define H_ 320
#define HS16_ 20          // H_/16 per-block h-slice
#define J_ 512
#define V_ 29
#define BLANK_ 28
#define MAXSYM_ 30
#define RESW_ (MAXSYM_ * T_)   // 15360

#define BM_ 128
#define BN_ 128
#define BK_ 16
#define GEMMB_ 1024       // GEMM blocks; aux (init) blocks appended after

// ---------------- static device memory ----------------
__device__ float g_Xi0[V_][4 * H_];      // wi0@emb[s]+bi0+bh0; row 28 = bias only
__device__ float g_b1s[4 * H_];          // bi1 + bh1
__device__ float g_h0x[2][N_][H_];       // exchange buffers (parity double-buffered)
__device__ float g_h1x[2][N_][H_];
__device__ float g_gpx[2][N_][16][J_];   // gproj partials per source block
__device__ unsigned int g_flag[N_];      // monotonic per-row sync counter

// ============================================================
// Kernel 1: Fproj GEMM + (tail blocks) Xi0 / b1s / flags / res-fill.
// Bs stored with a 4-float pad every 32 floats -> stride-8 reads max 2-way.
// ============================================================
#define BSW_ 144   // 128 + 4*4 pad
__device__ __forceinline__ int padcol(int c) { return c + ((c >> 5) << 2); }

__global__ __launch_bounds__(256) void gemm_init_kernel(
    const float* __restrict__ A, const float* __restrict__ B,
    const float* __restrict__ bj, float* __restrict__ C,
    const float* __restrict__ emb, const float* __restrict__ wi0,
    const float* __restrict__ bi0, const float* __restrict__ bh0,
    const float* __restrict__ bi1, const float* __restrict__ bh1,
    int* __restrict__ res) {
  const int bid = blockIdx.x;
  const int tid = threadIdx.x;

  if (bid >= GEMMB_) {
    const int ab = bid - GEMMB_;   // 0..31
    if (ab < V_) {
      // ---- Xi0 row ab (28 = null input) + b1s ----
      __shared__ __align__(16) float xs[H_];
      for (int i = tid; i < H_; i += 256)
        xs[i] = (ab < V_ - 1) ? emb[(size_t)ab * H_ + i] : 0.f;
      __syncthreads();
      for (int o = tid; o < 4 * H_; o += 256) {
        float acc = bi0[o] + bh0[o];
        if (ab < V_ - 1) {
          const float* wr = wi0 + (size_t)o * H_;
          for (int k = 0; k < H_; k += 4) {
            float4 x4 = *(const float4*)&xs[k];
            float4 w4 = *(const float4*)&wr[k];
            acc += x4.x * w4.x + x4.y * w4.y + x4.z * w4.z + x4.w * w4.w;
          }
        }
        g_Xi0[ab][o] = acc;
        if (ab == 0) g_b1s[o] = bi1[o] + bh1[o];
      }
    } else {
      // ---- 3 blocks: flag reset + res fill (int4) ----
      if (ab == V_ && tid < N_) g_flag[tid] = 0u;
      const int fb = ab - V_;             // 0..2
      int4* r4 = (int4*)res;
      const size_t tot = (size_t)N_ * RESW_ / 4;
      const size_t i0 = (size_t)fb * 256 + tid;
      const int4 mval = {-1, -1, -1, -1};
      for (size_t i = i0; i < tot; i += 3 * 256) r4[i] = mval;
    }
    return;
  }

  // ---------------- GEMM ----------------
  __shared__ __align__(16) float As[BK_][BM_ + 4];
  __shared__ __align__(16) float Bs[BK_][BSW_];
  const int m0 = blockIdx.x / 4 * BM_;
  const int j0 = (blockIdx.x & 3) * BN_;
  const int tx = tid & 15, ty = tid >> 4;
  const int sm = tid >> 1;
  const int sk = (tid & 1) << 3;
  const int smP = padcol(sm);
  const int bcol = padcol(tx * 8);   // tx*8 and tx*8+4 share a 32-block

  float acc[8][8];
#pragma unroll
  for (int i = 0; i < 8; ++i)
#pragma unroll
    for (int j = 0; j < 8; ++j) acc[i][j] = 0.f;

  for (int kc = 0; kc < E_; kc += BK_) {
    float4 av0 = *(const float4*)(A + (size_t)(m0 + sm) * E_ + kc + sk);
    float4 av1 = *(const float4*)(A + (size_t)(m0 + sm) * E_ + kc + sk + 4);
    float4 bv0 = *(const float4*)(B + (size_t)(j0 + sm) * E_ + kc + sk);
    float4 bv1 = *(const float4*)(B + (size_t)(j0 + sm) * E_ + kc + sk + 4);
    __syncthreads();
    As[sk + 0][sm] = av0.x; As[sk + 1][sm] = av0.y;
    As[sk + 2][sm] = av0.z; As[sk + 3][sm] = av0.w;
    As[sk + 4][sm] = av1.x; As[sk + 5][sm] = av1.y;
    As[sk + 6][sm] = av1.z; As[sk + 7][sm] = av1.w;
    Bs[sk + 0][smP] = bv0.x; Bs[sk + 1][smP] = bv0.y;
    Bs[sk + 2][smP] = bv0.z; Bs[sk + 3][smP] = bv0.w;
    Bs[sk + 4][smP] = bv1.x; Bs[sk + 5][smP] = bv1.y;
    Bs[sk + 6][smP] = bv1.z; Bs[sk + 7][smP] = bv1.w;
    __syncthreads();
#pragma unroll
    for (int k = 0; k < BK_; ++k) {
      float a_[8], b_[8];
      *(float4*)&a_[0] = *(const float4*)&As[k][ty * 8];
      *(float4*)&a_[4] = *(const float4*)&As[k][ty * 8 + 4];
      *(float4*)&b_[0] = *(const float4*)&Bs[k][bcol];
      *(float4*)&b_[4] = *(const float4*)&Bs[k][bcol + 4];
#pragma unroll
      for (int i = 0; i < 8; ++i)
#pragma unroll
        for (int j = 0; j < 8; ++j) acc[i][j] += a_[i] * b_[j];
    }
  }

#pragma unroll
  for (int i = 0; i < 8; ++i) {
    const size_t m = (size_t)(m0 + ty * 8 + i);
#pragma unroll
    for (int j = 0; j < 8; j += 4) {
      float4 v;
      v.x = acc[i][j + 0] + bj[j0 + tx * 8 + j + 0];
      v.y = acc[i][j + 1] + bj[j0 + tx * 8 + j + 1];
      v.z = acc[i][j + 2] + bj[j0 + tx * 8 + j + 2];
      v.w = acc[i][j + 3] + bj[j0 + tx * 8 + j + 3];
      *(float4*)(C + m * J_ + j0 + tx * 8 + j) = v;
    }
  }
}

// ============================================================
// decode helpers — 16-way split protocol
// ============================================================
__device__ __forceinline__ float sigmoidf_(float x) {
  return 1.f / (1.f + expf(-x));
}

__device__ __forceinline__ void flag_round16(int row, int tid, int& target) {
  target += 16;
  __syncthreads();  // all exchange stores issued/drained before flag
  if (tid == 0) {
    __hip_atomic_fetch_add(&g_flag[row], 1u, __ATOMIC_RELEASE,
                           __HIP_MEMORY_SCOPE_AGENT);
    while (__hip_atomic_load(&g_flag[row], __ATOMIC_ACQUIRE,
                             __HIP_MEMORY_SCOPE_AGENT) < (unsigned)target)
      __builtin_amdgcn_s_sleep(1);
  }
  __syncthreads();
}

// Recompute pending LSTM state + gproj from symbol s (28 = null).
// 2 flag rounds. 80 gate rows/block, 2 threads/row (k-range halves merged
// via shfl). c-state block-local (registers of threads 0..19).
__device__ void recompute16(
    int s, int row, int k16, int tid, int par, int& target,
    const float* __restrict__ wh0, const float* __restrict__ wi1,
    const float* __restrict__ wh1, const float* __restrict__ w_g,
    float* h0s, float* h1s, float* gates,
    float& c0, float& c1, float2& gp) {
  const int p = tid >> 1;             // gate-row index (valid < 80)
  const int half = tid & 1;
  const int g = p / HS16_;
  const int il = p - g * HS16_;
  const int o = g * H_ + k16 * HS16_ + il;
  const int k0 = half * (H_ / 2);     // 0 or 160

  // ---- layer 0 gates: Xi0[s][o] + wh0[o,:] @ h0_old (half-range each) ----
  if (p < 4 * HS16_) {
    const float* wr = wh0 + (size_t)o * H_;
    float acc = half ? 0.f : g_Xi0[s][o];
    for (int kk = k0; kk < k0 + H_ / 2; kk += 4) {
      float4 h4 = *(const float4*)&h0s[kk];
      float4 w4 = *(const float4*)&wr[kk];
      acc += h4.x * w4.x + h4.y * w4.y + h4.z * w4.z + h4.w * w4.w;
    }
    acc += __shfl_xor(acc, 1, 2);     // (Xi0 + lo-half) + hi-half on half==0
    if (half == 0) gates[p] = acc;
  }
  __syncthreads();
  if (tid < HS16_) {
    float ig = sigmoidf_(gates[tid]);
    float fg = sigmoidf_(gates[HS16_ + tid]);
    float gg = tanhf(gates[2 * HS16_ + tid]);
    float og = sigmoidf_(gates[3 * HS16_ + tid]);
    float c2 = fg * c0 + ig * gg;
    c0 = c2;
    float h2 = og * tanhf(c2);
    __hip_atomic_store(&g_h0x[par][row][k16 * HS16_ + tid], h2,
                       __ATOMIC_RELAXED, __HIP_MEMORY_SCOPE_AGENT);
  }
  // ---- overlap S1 wait with wh1 @ h1_old (half-range) ----
  float acc1 = 0.f;
  if (p < 4 * HS16_) {
    const float* whr = wh1 + (size_t)o * H_;
    acc1 = half ? 0.f : g_b1s[o];
    for (int kk = k0; kk < k0 + H_ / 2; kk += 4) {
      float4 h4 = *(const float4*)&h1s[kk];
      float4 w4 = *(const float4*)&whr[kk];
      acc1 += h4.x * w4.x + h4.y * w4.y + h4.z * w4.z + h4.w * w4.w;
    }
  }
  flag_round16(row, tid, target);   // S1: h0 slices ready
  h0s[tid] = __hip_atomic_load(&g_h0x[par][row][tid], __ATOMIC_RELAXED,
                               __HIP_MEMORY_SCOPE_AGENT);
  if (tid < H_ - 256)
    h0s[256 + tid] = __hip_atomic_load(&g_h0x[par][row][256 + tid],
                                       __ATOMIC_RELAXED, __HIP_MEMORY_SCOPE_AGENT);
  __syncthreads();
  // ---- layer1 gates += wi1[o,:] @ h0_new (half-range), merge halves ----
  if (p < 4 * HS16_) {
    const float* wir = wi1 + (size_t)o * H_;
    for (int kk = k0; kk < k0 + H_ / 2; kk += 4) {
      float4 x4 = *(const float4*)&h0s[kk];
      float4 w4 = *(const float4*)&wir[kk];
      acc1 += x4.x * w4.x + x4.y * w4.y + x4.z * w4.z + x4.w * w4.w;
    }
    acc1 += __shfl_xor(acc1, 1, 2);
    if (half == 0) gates[p] = acc1;
  }
  __syncthreads();
  if (tid < HS16_) {
    float ig = sigmoidf_(gates[tid]);
    float fg = sigmoidf_(gates[HS16_ + tid]);
    float gg = tanhf(gates[2 * HS16_ + tid]);
    float og = sigmoidf_(gates[3 * HS16_ + tid]);
    float c2 = fg * c1 + ig * gg;
    c1 = c2;
    float h2 = og * tanhf(c2);
    h1s[k16 * HS16_ + tid] = h2;
    __hip_atomic_store(&g_h1x[par][row][k16 * HS16_ + tid], h2,
                       __ATOMIC_RELAXED, __HIP_MEMORY_SCOPE_AGENT);
  }
  __syncthreads();
  // ---- gproj partials over own 20-wide h1 slice: j = tid, tid+256 ----
  {
    const float* hsl = &h1s[k16 * HS16_];
#pragma unroll
    for (int jj = 0; jj < 2; ++jj) {
      const int j = tid + jj * 256;
      const float* wgr = w_g + (size_t)j * H_ + k16 * HS16_;
      float a = 0.f;
#pragma unroll
      for (int kk = 0; kk < HS16_; kk += 4) {
        float4 h4 = *(const float4*)&hsl[kk];
        float4 w4 = *(const float4*)&wgr[kk];
        a += h4.x * w4.x + h4.y * w4.y + h4.z * w4.z + h4.w * w4.w;
      }
      __hip_atomic_store(&g_gpx[par][row][k16][j], a, __ATOMIC_RELAXED,
                         __HIP_MEMORY_SCOPE_AGENT);
    }
  }
  flag_round16(row, tid, target);   // S2: h1 slices + gp partials ready
  {
    float ax = 0.f, ay = 0.f;
#pragma unroll
    for (int kk = 0; kk < 16; ++kk) {
      ax += __hip_atomic_load(&g_gpx[par][row][kk][2 * tid], __ATOMIC_RELAXED,
                              __HIP_MEMORY_SCOPE_AGENT);
      ay += __hip_atomic_load(&g_gpx[par][row][kk][2 * tid + 1], __ATOMIC_RELAXED,
                              __HIP_MEMORY_SCOPE_AGENT);
    }
    gp.x = ax; gp.y = ay;
  }
  h1s[tid] = __hip_atomic_load(&g_h1x[par][row][tid], __ATOMIC_RELAXED,
                               __HIP_MEMORY_SCOPE_AGENT);
  if (tid < H_ - 256)
    h1s[256 + tid] = __hip_atomic_load(&g_h1x[par][row][256 + tid],
                                       __ATOMIC_RELAXED, __HIP_MEMORY_SCOPE_AGENT);
  __syncthreads();
}

// ============================================================
// Kernel 2: decode, 16 blocks/row x 256 threads (1024 blocks, 4/CU).
// waves_per_eu(4,4) pins the allocator at the 128-VGPR budget: r10's
// allocator squeezed to 64 VGPR (8 waves/EU) and spilled wo[16].
// ============================================================
__global__ __launch_bounds__(256, 4)
__attribute__((amdgpu_waves_per_eu(4, 4))) void decode16(
    const float* __restrict__ Fproj, const int* __restrict__ f_lens,
    const float* __restrict__ wh0,
    const float* __restrict__ wi1, const float* __restrict__ wh1,
    const float* __restrict__ w_g,
    const float* __restrict__ w_o, const float* __restrict__ b_o,
    int* __restrict__ res, int* __restrict__ nsym) {
  const int bid = blockIdx.x;
  const int k16 = bid & 15;                      // slice -> XCD (bid%8 pins pairs)
  const int row = ((bid >> 4) + 4 * k16) & 63;   // scrambled co-residency
  const int tid = threadIdx.x;
  const int f_len = f_lens[row];

  __shared__ __align__(16) float h0s[H_], h1s[H_];
  __shared__ __align__(16) float gates[4 * HS16_];
  __shared__ __align__(16) float hjs[J_];
  __shared__ float logits[32];

  // blank-path: v = tid>>3 (vocab word), lq = tid&7; lane covers
  // j = lq*4 + 32*q + e (q<16, e<4) -> 16 float4, bank-spread
  const int v = tid >> 3;
  const int lq = tid & 7;
  float4 wo[16];
  float bo = 0.f;
  if (v < V_) {
#pragma unroll
    for (int q = 0; q < 16; ++q)
      wo[q] = *(const float4*)(w_o + (size_t)v * J_ + lq * 4 + 32 * q);
    bo = b_o[v];
  }

  for (int i = tid; i < H_; i += 256) { h0s[i] = 0.f; h1s[i] = 0.f; }
  float c0 = 0.f, c1 = 0.f;
  float2 gp = {0.f, 0.f};
  int target = 0;
  __syncthreads();

  // initial pending state from (last=-1, h=0, c=0)
  recompute16(BLANK_, row, k16, tid, 0, target, wh0, wi1, wh1, w_g,
              h0s, h1s, gates, c0, c1, gp);
  int ecount = 1;

  int t_loc = 0, sym_add = 0, res_idx = -1;
  float2 fp = *(const float2*)(Fproj + (size_t)row * J_ + 2 * tid);  // t=0

  while (t_loc < f_len) {
    const int tn = (t_loc + 1 < T_) ? t_loc + 1 : T_ - 1;
    float2 fpn = *(const float2*)(Fproj + ((size_t)tn * N_ + row) * J_ + 2 * tid);

    float hx = fp.x + gp.x, hy = fp.y + gp.y;
    float2 hj2 = {hx > 0.f ? hx : 0.f, hy > 0.f ? hy : 0.f};
    *(float2*)&hjs[2 * tid] = hj2;
    __syncthreads();                    // B1

    float p = 0.f;
    if (v < V_) {
#pragma unroll
      for (int q = 0; q < 16; ++q) {
        float4 h4 = *(const float4*)&hjs[lq * 4 + 32 * q];
        p += h4.x * wo[q].x + h4.y * wo[q].y + h4.z * wo[q].z + h4.w * wo[q].w;
      }
    }
    p += __shfl_xor(p, 4, 8);
    p += __shfl_xor(p, 2, 8);
    p += __shfl_xor(p, 1, 8);
    if (v < V_ && lq == 0) logits[v] = p + bo;
    __syncthreads();                    // B2

    // redundant argmax (first-max tie-break, identical everywhere)
    float best = logits[0];
    int bi = 0;
#pragma unroll
    for (int vv = 1; vv < V_; ++vv) {
      float lv = logits[vv];
      if (lv > best) { best = lv; bi = vv; }
    }
    const int emit = (bi != BLANK_) && (sym_add < MAXSYM_);

    if (emit) {
      res_idx += 1;
      if (k16 == 0 && tid == 0) res[(size_t)row * RESW_ + res_idx] = bi;
      sym_add += 1;
      recompute16(bi, row, k16, tid, ecount & 1, target, wh0, wi1, wh1, w_g,
                  h0s, h1s, gates, c0, c1, gp);
      ecount += 1;
    } else {
      sym_add = 0;
      t_loc += 1;
      fp = fpn;
    }
  }

  if (k16 == 0 && tid == 0) nsym[row] = res_idx + 1;
}

// ============================================================
extern "C" void kernel_launch(void* const* d_in, const int* in_sizes, int n_in,
                              void* d_out, int out_size, void* d_ws, size_t ws_size,
                              hipStream_t stream) {
  const float* f      = (const float*)d_in[0];
  const int*   f_lens = (const int*)d_in[1];
  const float* emb    = (const float*)d_in[2];
  const float* wi0    = (const float*)d_in[3];
  const float* wh0    = (const float*)d_in[4];
  const float* bi0    = (const float*)d_in[5];
  const float* bh0    = (const float*)d_in[6];
  const float* wi1    = (const float*)d_in[7];
  const float* wh1    = (const float*)d_in[8];
  const float* bi1    = (const float*)d_in[9];
  const float* bh1    = (const float*)d_in[10];
  const float* w_f    = (const float*)d_in[11];
  const float* w_g    = (const float*)d_in[12];
  const float* b_j    = (const float*)d_in[13];
  const float* w_o    = (const float*)d_in[14];
  const float* b_o    = (const float*)d_in[15];

  int* out  = (int*)d_out;
  int* res  = out;                       // (64, 15360)
  int* nsym = out + (size_t)N_ * RESW_;  // (64,)

  float* Fproj = (float*)d_ws;  // T*N*J*4 = 64 MiB

  gemm_init_kernel<<<GEMMB_ + 32, 256, 0, stream>>>(
      f, w_f, b_j, Fproj, emb, wi0, bi0, bh0, bi1, bh1, res);

  decode16<<<N_ * 16, 256, 0, stream>>>(Fproj, f_lens, wh0, wi1, wh1, w_g,
                                        w_o, b_o, res, nsym);
}

// Round 12
// 1859.242 us; speedup vs baseline: 1.1828x; 1.1828x over previous
//
#include <hip/hip_runtime.h>
#include <math.h>

#define T_ 512
#define N_ 64
#define E_ 1024
#define H_ 320
#define HS16_ 20          // H_/16 per-block h-slice
#define J_ 512
#define V_ 29
#define BLANK_ 28
#define MAXSYM_ 30
#define RESW_ (MAXSYM_ * T_)   // 15360

#define BM_ 128
#define BN_ 128
#define BK_ 16
#define GEMMB_ 1024       // GEMM blocks; aux (init) blocks appended after

// ---------------- static device memory ----------------
__device__ float g_Xi0[V_][4 * H_];      // wi0@emb[s]+bi0+bh0; row 28 = bias only
__device__ float g_b1s[4 * H_];          // bi1 + bh1
__device__ float g_h0x[2][N_][H_];       // exchange buffers (parity double-buffered)
__device__ float g_h1x[2][N_][H_];
__device__ float g_gpx[2][N_][16][J_];   // gproj partials per source block
__device__ unsigned int g_flag[N_];      // monotonic per-row sync counter

// ============================================================
// Kernel 1: Fproj GEMM + (tail blocks) Xi0 / b1s / flags / res-fill.
// ============================================================
#define BSW_ 144   // 128 + 4*4 pad
__device__ __forceinline__ int padcol(int c) { return c + ((c >> 5) << 2); }

__global__ __launch_bounds__(256) void gemm_init_kernel(
    const float* __restrict__ A, const float* __restrict__ B,
    const float* __restrict__ bj, float* __restrict__ C,
    const float* __restrict__ emb, const float* __restrict__ wi0,
    const float* __restrict__ bi0, const float* __restrict__ bh0,
    const float* __restrict__ bi1, const float* __restrict__ bh1,
    int* __restrict__ res) {
  const int bid = blockIdx.x;
  const int tid = threadIdx.x;

  if (bid >= GEMMB_) {
    const int ab = bid - GEMMB_;   // 0..31
    if (ab < V_) {
      // ---- Xi0 row ab (28 = null input) + b1s ----
      __shared__ __align__(16) float xs[H_];
      for (int i = tid; i < H_; i += 256)
        xs[i] = (ab < V_ - 1) ? emb[(size_t)ab * H_ + i] : 0.f;
      __syncthreads();
      for (int o = tid; o < 4 * H_; o += 256) {
        float acc = bi0[o] + bh0[o];
        if (ab < V_ - 1) {
          const float* wr = wi0 + (size_t)o * H_;
          for (int k = 0; k < H_; k += 4) {
            float4 x4 = *(const float4*)&xs[k];
            float4 w4 = *(const float4*)&wr[k];
            acc += x4.x * w4.x + x4.y * w4.y + x4.z * w4.z + x4.w * w4.w;
          }
        }
        g_Xi0[ab][o] = acc;
        if (ab == 0) g_b1s[o] = bi1[o] + bh1[o];
      }
    } else {
      // ---- 3 blocks: flag reset + res fill (int4) ----
      if (ab == V_ && tid < N_) g_flag[tid] = 0u;
      const int fb = ab - V_;             // 0..2
      int4* r4 = (int4*)res;
      const size_t tot = (size_t)N_ * RESW_ / 4;
      const size_t i0 = (size_t)fb * 256 + tid;
      const int4 mval = {-1, -1, -1, -1};
      for (size_t i = i0; i < tot; i += 3 * 256) r4[i] = mval;
    }
    return;
  }

  // ---------------- GEMM ----------------
  __shared__ __align__(16) float As[BK_][BM_ + 4];
  __shared__ __align__(16) float Bs[BK_][BSW_];
  const int m0 = blockIdx.x / 4 * BM_;
  const int j0 = (blockIdx.x & 3) * BN_;
  const int tx = tid & 15, ty = tid >> 4;
  const int sm = tid >> 1;
  const int sk = (tid & 1) << 3;
  const int smP = padcol(sm);
  const int bcol = padcol(tx * 8);   // tx*8 and tx*8+4 share a 32-block

  float acc[8][8];
#pragma unroll
  for (int i = 0; i < 8; ++i)
#pragma unroll
    for (int j = 0; j < 8; ++j) acc[i][j] = 0.f;

  for (int kc = 0; kc < E_; kc += BK_) {
    float4 av0 = *(const float4*)(A + (size_t)(m0 + sm) * E_ + kc + sk);
    float4 av1 = *(const float4*)(A + (size_t)(m0 + sm) * E_ + kc + sk + 4);
    float4 bv0 = *(const float4*)(B + (size_t)(j0 + sm) * E_ + kc + sk);
    float4 bv1 = *(const float4*)(B + (size_t)(j0 + sm) * E_ + kc + sk + 4);
    __syncthreads();
    As[sk + 0][sm] = av0.x; As[sk + 1][sm] = av0.y;
    As[sk + 2][sm] = av0.z; As[sk + 3][sm] = av0.w;
    As[sk + 4][sm] = av1.x; As[sk + 5][sm] = av1.y;
    As[sk + 6][sm] = av1.z; As[sk + 7][sm] = av1.w;
    Bs[sk + 0][smP] = bv0.x; Bs[sk + 1][smP] = bv0.y;
    Bs[sk + 2][smP] = bv0.z; Bs[sk + 3][smP] = bv0.w;
    Bs[sk + 4][smP] = bv1.x; Bs[sk + 5][smP] = bv1.y;
    Bs[sk + 6][smP] = bv1.z; Bs[sk + 7][smP] = bv1.w;
    __syncthreads();
#pragma unroll
    for (int k = 0; k < BK_; ++k) {
      float a_[8], b_[8];
      *(float4*)&a_[0] = *(const float4*)&As[k][ty * 8];
      *(float4*)&a_[4] = *(const float4*)&As[k][ty * 8 + 4];
      *(float4*)&b_[0] = *(const float4*)&Bs[k][bcol];
      *(float4*)&b_[4] = *(const float4*)&Bs[k][bcol + 4];
#pragma unroll
      for (int i = 0; i < 8; ++i)
#pragma unroll
        for (int j = 0; j < 8; ++j) acc[i][j] += a_[i] * b_[j];
    }
  }

#pragma unroll
  for (int i = 0; i < 8; ++i) {
    const size_t m = (size_t)(m0 + ty * 8 + i);
#pragma unroll
    for (int j = 0; j < 8; j += 4) {
      float4 v;
      v.x = acc[i][j + 0] + bj[j0 + tx * 8 + j + 0];
      v.y = acc[i][j + 1] + bj[j0 + tx * 8 + j + 1];
      v.z = acc[i][j + 2] + bj[j0 + tx * 8 + j + 2];
      v.w = acc[i][j + 3] + bj[j0 + tx * 8 + j + 3];
      *(float4*)(C + m * J_ + j0 + tx * 8 + j) = v;
    }
  }
}

// ============================================================
// decode helpers — 16-way split protocol
// ============================================================
__device__ __forceinline__ float sigmoidf_(float x) {
  return 1.f / (1.f + expf(-x));
}

__device__ __forceinline__ void flag_round16(int row, int tid, int& target) {
  target += 16;
  __syncthreads();  // all exchange stores issued/drained before flag
  if (tid == 0) {
    __hip_atomic_fetch_add(&g_flag[row], 1u, __ATOMIC_RELEASE,
                           __HIP_MEMORY_SCOPE_AGENT);
    while (__hip_atomic_load(&g_flag[row], __ATOMIC_ACQUIRE,
                             __HIP_MEMORY_SCOPE_AGENT) < (unsigned)target)
      __builtin_amdgcn_s_sleep(1);
  }
  __syncthreads();
}

// Recompute pending LSTM state + gproj from symbol s (28 = null).
// 2 flag rounds. 80 gate rows/block, 2 threads/row (k-range halves merged
// via shfl). c-state block-local (registers of threads 0..19).
__device__ void recompute16(
    int s, int row, int k16, int tid, int par, int& target,
    const float* __restrict__ wh0, const float* __restrict__ wi1,
    const float* __restrict__ wh1, const float* __restrict__ w_g,
    float* h0s, float* h1s, float* gates,
    float& c0, float& c1, float2& gp) {
  const int p = tid >> 1;             // gate-row index (valid < 80)
  const int half = tid & 1;
  const int g = p / HS16_;
  const int il = p - g * HS16_;
  const int o = g * H_ + k16 * HS16_ + il;
  const int k0 = half * (H_ / 2);     // 0 or 160

  // ---- layer 0 gates: Xi0[s][o] + wh0[o,:] @ h0_old (half-range each) ----
  if (p < 4 * HS16_) {
    const float* wr = wh0 + (size_t)o * H_;
    float acc = half ? 0.f : g_Xi0[s][o];
    for (int kk = k0; kk < k0 + H_ / 2; kk += 4) {
      float4 h4 = *(const float4*)&h0s[kk];
      float4 w4 = *(const float4*)&wr[kk];
      acc += h4.x * w4.x + h4.y * w4.y + h4.z * w4.z + h4.w * w4.w;
    }
    acc += __shfl_xor(acc, 1, 2);     // (Xi0 + lo-half) + hi-half on half==0
    if (half == 0) gates[p] = acc;
  }
  __syncthreads();
  if (tid < HS16_) {
    float ig = sigmoidf_(gates[tid]);
    float fg = sigmoidf_(gates[HS16_ + tid]);
    float gg = tanhf(gates[2 * HS16_ + tid]);
    float og = sigmoidf_(gates[3 * HS16_ + tid]);
    float c2 = fg * c0 + ig * gg;
    c0 = c2;
    float h2 = og * tanhf(c2);
    __hip_atomic_store(&g_h0x[par][row][k16 * HS16_ + tid], h2,
                       __ATOMIC_RELAXED, __HIP_MEMORY_SCOPE_AGENT);
  }
  // ---- overlap S1 wait with wh1 @ h1_old (half-range) ----
  float acc1 = 0.f;
  if (p < 4 * HS16_) {
    const float* whr = wh1 + (size_t)o * H_;
    acc1 = half ? 0.f : g_b1s[o];
    for (int kk = k0; kk < k0 + H_ / 2; kk += 4) {
      float4 h4 = *(const float4*)&h1s[kk];
      float4 w4 = *(const float4*)&whr[kk];
      acc1 += h4.x * w4.x + h4.y * w4.y + h4.z * w4.z + h4.w * w4.w;
    }
  }
  flag_round16(row, tid, target);   // S1: h0 slices ready
  h0s[tid] = __hip_atomic_load(&g_h0x[par][row][tid], __ATOMIC_RELAXED,
                               __HIP_MEMORY_SCOPE_AGENT);
  if (tid < H_ - 256)
    h0s[256 + tid] = __hip_atomic_load(&g_h0x[par][row][256 + tid],
                                       __ATOMIC_RELAXED, __HIP_MEMORY_SCOPE_AGENT);
  __syncthreads();
  // ---- layer1 gates += wi1[o,:] @ h0_new (half-range), merge halves ----
  if (p < 4 * HS16_) {
    const float* wir = wi1 + (size_t)o * H_;
    for (int kk = k0; kk < k0 + H_ / 2; kk += 4) {
      float4 x4 = *(const float4*)&h0s[kk];
      float4 w4 = *(const float4*)&wir[kk];
      acc1 += x4.x * w4.x + x4.y * w4.y + x4.z * w4.z + x4.w * w4.w;
    }
    acc1 += __shfl_xor(acc1, 1, 2);
    if (half == 0) gates[p] = acc1;
  }
  __syncthreads();
  if (tid < HS16_) {
    float ig = sigmoidf_(gates[tid]);
    float fg = sigmoidf_(gates[HS16_ + tid]);
    float gg = tanhf(gates[2 * HS16_ + tid]);
    float og = sigmoidf_(gates[3 * HS16_ + tid]);
    float c2 = fg * c1 + ig * gg;
    c1 = c2;
    float h2 = og * tanhf(c2);
    h1s[k16 * HS16_ + tid] = h2;
    __hip_atomic_store(&g_h1x[par][row][k16 * HS16_ + tid], h2,
                       __ATOMIC_RELAXED, __HIP_MEMORY_SCOPE_AGENT);
  }
  __syncthreads();
  // ---- gproj partials over own 20-wide h1 slice: j = tid, tid+256 ----
  {
    const float* hsl = &h1s[k16 * HS16_];
#pragma unroll
    for (int jj = 0; jj < 2; ++jj) {
      const int j = tid + jj * 256;
      const float* wgr = w_g + (size_t)j * H_ + k16 * HS16_;
      float a = 0.f;
#pragma unroll
      for (int kk = 0; kk < HS16_; kk += 4) {
        float4 h4 = *(const float4*)&hsl[kk];
        float4 w4 = *(const float4*)&wgr[kk];
        a += h4.x * w4.x + h4.y * w4.y + h4.z * w4.z + h4.w * w4.w;
      }
      __hip_atomic_store(&g_gpx[par][row][k16][j], a, __ATOMIC_RELAXED,
                         __HIP_MEMORY_SCOPE_AGENT);
    }
  }
  flag_round16(row, tid, target);   // S2: h1 slices + gp partials ready
  {
    float ax = 0.f, ay = 0.f;
#pragma unroll
    for (int kk = 0; kk < 16; ++kk) {
      ax += __hip_atomic_load(&g_gpx[par][row][kk][2 * tid], __ATOMIC_RELAXED,
                              __HIP_MEMORY_SCOPE_AGENT);
      ay += __hip_atomic_load(&g_gpx[par][row][kk][2 * tid + 1], __ATOMIC_RELAXED,
                              __HIP_MEMORY_SCOPE_AGENT);
    }
    gp.x = ax; gp.y = ay;
  }
  h1s[tid] = __hip_atomic_load(&g_h1x[par][row][tid], __ATOMIC_RELAXED,
                               __HIP_MEMORY_SCOPE_AGENT);
  if (tid < H_ - 256)
    h1s[256 + tid] = __hip_atomic_load(&g_h1x[par][row][256 + tid],
                                       __ATOMIC_RELAXED, __HIP_MEMORY_SCOPE_AGENT);
  __syncthreads();
}

// ============================================================
// Kernel 2: decode, 16 blocks/row x 256 threads (1024 blocks, 4/CU).
// w_o split: q=0..7 in registers (32 VGPR), q=8..15 in LDS (32 KB) ->
// per-thread live regs ~60 <= the allocator's 64 budget, no spill.
// ============================================================
__global__ __launch_bounds__(256, 4) void decode16(
    const float* __restrict__ Fproj, const int* __restrict__ f_lens,
    const float* __restrict__ wh0,
    const float* __restrict__ wi1, const float* __restrict__ wh1,
    const float* __restrict__ w_g,
    const float* __restrict__ w_o, const float* __restrict__ b_o,
    int* __restrict__ res, int* __restrict__ nsym) {
  const int bid = blockIdx.x;
  const int k16 = bid & 15;                      // slice -> XCD (bid%8 pins pairs)
  const int row = ((bid >> 4) + 4 * k16) & 63;   // scrambled co-residency
  const int tid = threadIdx.x;
  const int f_len = f_lens[row];

  __shared__ __align__(16) float h0s[H_], h1s[H_];
  __shared__ __align__(16) float gates[4 * HS16_];
  __shared__ __align__(16) float hjs[J_];
  __shared__ __align__(16) float woL[8][256][4];  // w_o q=8..15, own-slot reads
  __shared__ float logits[32];

  // blank-path: v = tid>>3 (vocab word), lq = tid&7; lane covers
  // j = lq*4 + 32*q + e (q<16, e<4); q=0..7 regs, q=8..15 LDS
  const int v = tid >> 3;
  const int lq = tid & 7;
  float4 wo[8];
  float bo = 0.f;
#pragma unroll
  for (int q = 0; q < 8; ++q) {
    float4 z = {0.f, 0.f, 0.f, 0.f};
    wo[q] = (v < V_) ? *(const float4*)(w_o + (size_t)v * J_ + lq * 4 + 32 * q) : z;
    *(float4*)&woL[q][tid][0] =
        (v < V_) ? *(const float4*)(w_o + (size_t)v * J_ + lq * 4 + 32 * (q + 8)) : z;
  }
  if (v < V_) bo = b_o[v];

  for (int i = tid; i < H_; i += 256) { h0s[i] = 0.f; h1s[i] = 0.f; }
  float c0 = 0.f, c1 = 0.f;
  float2 gp = {0.f, 0.f};
  int target = 0;
  __syncthreads();

  // initial pending state from (last=-1, h=0, c=0)
  recompute16(BLANK_, row, k16, tid, 0, target, wh0, wi1, wh1, w_g,
              h0s, h1s, gates, c0, c1, gp);
  int ecount = 1;

  int t_loc = 0, sym_add = 0, res_idx = -1;
  float2 fp = *(const float2*)(Fproj + (size_t)row * J_ + 2 * tid);  // t=0

  while (t_loc < f_len) {
    const int tn = (t_loc + 1 < T_) ? t_loc + 1 : T_ - 1;
    float2 fpn = *(const float2*)(Fproj + ((size_t)tn * N_ + row) * J_ + 2 * tid);

    float hx = fp.x + gp.x, hy = fp.y + gp.y;
    float2 hj2 = {hx > 0.f ? hx : 0.f, hy > 0.f ? hy : 0.f};
    *(float2*)&hjs[2 * tid] = hj2;
    __syncthreads();                    // B1

    float p = 0.f;
    if (v < V_) {
#pragma unroll
      for (int q = 0; q < 8; ++q) {
        float4 h4 = *(const float4*)&hjs[lq * 4 + 32 * q];
        p += h4.x * wo[q].x + h4.y * wo[q].y + h4.z * wo[q].z + h4.w * wo[q].w;
      }
#pragma unroll
      for (int q = 8; q < 16; ++q) {
        float4 h4 = *(const float4*)&hjs[lq * 4 + 32 * q];
        float4 w4 = *(const float4*)&woL[q - 8][tid][0];
        p += h4.x * w4.x + h4.y * w4.y + h4.z * w4.z + h4.w * w4.w;
      }
    }
    p += __shfl_xor(p, 4, 8);
    p += __shfl_xor(p, 2, 8);
    p += __shfl_xor(p, 1, 8);
    if (v < V_ && lq == 0) logits[v] = p + bo;
    __syncthreads();                    // B2

    // redundant argmax (first-max tie-break, identical everywhere)
    float best = logits[0];
    int bi = 0;
#pragma unroll
    for (int vv = 1; vv < V_; ++vv) {
      float lv = logits[vv];
      if (lv > best) { best = lv; bi = vv; }
    }
    const int emit = (bi != BLANK_) && (sym_add < MAXSYM_);

    if (emit) {
      res_idx += 1;
      if (k16 == 0 && tid == 0) res[(size_t)row * RESW_ + res_idx] = bi;
      sym_add += 1;
      recompute16(bi, row, k16, tid, ecount & 1, target, wh0, wi1, wh1, w_g,
                  h0s, h1s, gates, c0, c1, gp);
      ecount += 1;
    } else {
      sym_add = 0;
      t_loc += 1;
      fp = fpn;
    }
  }

  if (k16 == 0 && tid == 0) nsym[row] = res_idx + 1;
}

// ============================================================
extern "C" void kernel_launch(void* const* d_in, const int* in_sizes, int n_in,
                              void* d_out, int out_size, void* d_ws, size_t ws_size,
                              hipStream_t stream) {
  const float* f      = (const float*)d_in[0];
  const int*   f_lens = (const int*)d_in[1];
  const float* emb    = (const float*)d_in[2];
  const float* wi0    = (const float*)d_in[3];
  const float* wh0    = (const float*)d_in[4];
  const float* bi0    = (const float*)d_in[5];
  const float* bh0    = (const float*)d_in[6];
  const float* wi1    = (const float*)d_in[7];
  const float* wh1    = (const float*)d_in[8];
  const float* bi1    = (const float*)d_in[9];
  const float* bh1    = (const float*)d_in[10];
  const float* w_f    = (const float*)d_in[11];
  const float* w_g    = (const float*)d_in[12];
  const float* b_j    = (const float*)d_in[13];
  const float* w_o    = (const float*)d_in[14];
  const float* b_o    = (const float*)d_in[15];

  int* out  = (int*)d_out;
  int* res  = out;                       // (64, 15360)
  int* nsym = out + (size_t)N_ * RESW_;  // (64,)

  float* Fproj = (float*)d_ws;  // T*N*J*4 = 64 MiB

  gemm_init_kernel<<<GEMMB_ + 32, 256, 0, stream>>>(
      f, w_f, b_j, Fproj, emb, wi0, bi0, bh0, bi1, bh1, res);

  decode16<<<N_ * 16, 256, 0, stream>>>(Fproj, f_lens, wh0, wi1, wh1, w_g,
                                        w_o, b_o, res, nsym);
}

// Round 13
// 1836.672 us; speedup vs baseline: 1.1973x; 1.0123x over previous
//
#include <hip/hip_runtime.h>
#include <math.h>

#define T_ 512
#define N_ 64
#define E_ 1024
#define H_ 320
#define HS16_ 20          // H_/16 per-block h-slice
#define J_ 512
#define V_ 29
#define BLANK_ 28
#define MAXSYM_ 30
#define RESW_ (MAXSYM_ * T_)   // 15360

#define BM_ 128
#define BN_ 128
#define BK_ 16
#define GEMMB_ 1024       // GEMM blocks; aux (init) blocks appended after

// ---------------- static device memory ----------------
__device__ float g_Xi0[V_][4 * H_];      // wi0@emb[s]+bi0+bh0; row 28 = bias only
__device__ float g_b1s[4 * H_];          // bi1 + bh1
__device__ float g_h0x[2][N_][H_];       // exchange buffers (parity double-buffered)
__device__ float g_h1x[2][N_][H_];
__device__ float g_gpx[2][N_][16][J_];   // gproj partials per source block
__device__ unsigned int g_flag[N_];      // monotonic per-row sync counter

// ============================================================
// Kernel 1: Fproj GEMM (double-buffered LDS, 1 barrier/K-tile)
// + (tail blocks) Xi0 / b1s / flags / res-fill.
// ============================================================
#define BSW_ 144   // 128 + 4*4 pad
__device__ __forceinline__ int padcol(int c) { return c + ((c >> 5) << 2); }

__global__ __launch_bounds__(256) void gemm_init_kernel(
    const float* __restrict__ A, const float* __restrict__ B,
    const float* __restrict__ bj, float* __restrict__ C,
    const float* __restrict__ emb, const float* __restrict__ wi0,
    const float* __restrict__ bi0, const float* __restrict__ bh0,
    const float* __restrict__ bi1, const float* __restrict__ bh1,
    int* __restrict__ res) {
  const int bid = blockIdx.x;
  const int tid = threadIdx.x;

  if (bid >= GEMMB_) {
    const int ab = bid - GEMMB_;   // 0..31
    if (ab < V_) {
      // ---- Xi0 row ab (28 = null input) + b1s ----
      __shared__ __align__(16) float xs[H_];
      for (int i = tid; i < H_; i += 256)
        xs[i] = (ab < V_ - 1) ? emb[(size_t)ab * H_ + i] : 0.f;
      __syncthreads();
      for (int o = tid; o < 4 * H_; o += 256) {
        float acc = bi0[o] + bh0[o];
        if (ab < V_ - 1) {
          const float* wr = wi0 + (size_t)o * H_;
          for (int k = 0; k < H_; k += 4) {
            float4 x4 = *(const float4*)&xs[k];
            float4 w4 = *(const float4*)&wr[k];
            acc += x4.x * w4.x + x4.y * w4.y + x4.z * w4.z + x4.w * w4.w;
          }
        }
        g_Xi0[ab][o] = acc;
        if (ab == 0) g_b1s[o] = bi1[o] + bh1[o];
      }
    } else {
      // ---- 3 blocks: flag reset + res fill (int4) ----
      if (ab == V_ && tid < N_) g_flag[tid] = 0u;
      const int fb = ab - V_;             // 0..2
      int4* r4 = (int4*)res;
      const size_t tot = (size_t)N_ * RESW_ / 4;
      const size_t i0 = (size_t)fb * 256 + tid;
      const int4 mval = {-1, -1, -1, -1};
      for (size_t i = i0; i < tot; i += 3 * 256) r4[i] = mval;
    }
    return;
  }

  // ---------------- GEMM (double-buffered) ----------------
  __shared__ __align__(16) float As[2][BK_][BM_ + 4];
  __shared__ __align__(16) float Bs[2][BK_][BSW_];
  const int m0 = blockIdx.x / 4 * BM_;
  const int j0 = (blockIdx.x & 3) * BN_;
  const int tx = tid & 15, ty = tid >> 4;
  const int sm = tid >> 1;
  const int sk = (tid & 1) << 3;
  const int smP = padcol(sm);
  const int bcol = padcol(tx * 8);   // tx*8 and tx*8+4 share a 32-block

  float acc[8][8];
#pragma unroll
  for (int i = 0; i < 8; ++i)
#pragma unroll
    for (int j = 0; j < 8; ++j) acc[i][j] = 0.f;

  const float* arow = A + (size_t)(m0 + sm) * E_ + sk;
  const float* brow = B + (size_t)(j0 + sm) * E_ + sk;

  // preload K-tile 0
  float4 av0 = *(const float4*)(arow + 0);
  float4 av1 = *(const float4*)(arow + 4);
  float4 bv0 = *(const float4*)(brow + 0);
  float4 bv1 = *(const float4*)(brow + 4);

  const int NIT = E_ / BK_;  // 64
  for (int it = 0; it < NIT; ++it) {
    const int cur = it & 1;
    // store staged regs -> LDS[cur]
    As[cur][sk + 0][sm] = av0.x; As[cur][sk + 1][sm] = av0.y;
    As[cur][sk + 2][sm] = av0.z; As[cur][sk + 3][sm] = av0.w;
    As[cur][sk + 4][sm] = av1.x; As[cur][sk + 5][sm] = av1.y;
    As[cur][sk + 6][sm] = av1.z; As[cur][sk + 7][sm] = av1.w;
    Bs[cur][sk + 0][smP] = bv0.x; Bs[cur][sk + 1][smP] = bv0.y;
    Bs[cur][sk + 2][smP] = bv0.z; Bs[cur][sk + 3][smP] = bv0.w;
    Bs[cur][sk + 4][smP] = bv1.x; Bs[cur][sk + 5][smP] = bv1.y;
    Bs[cur][sk + 6][smP] = bv1.z; Bs[cur][sk + 7][smP] = bv1.w;
    __syncthreads();   // single barrier: separates it-1 reads from it+1 writes
    // issue next tile's global loads (latency hides under compute)
    if (it + 1 < NIT) {
      const int kc = (it + 1) * BK_;
      av0 = *(const float4*)(arow + kc);
      av1 = *(const float4*)(arow + kc + 4);
      bv0 = *(const float4*)(brow + kc);
      bv1 = *(const float4*)(brow + kc + 4);
    }
    // compute from LDS[cur]
#pragma unroll
    for (int k = 0; k < BK_; ++k) {
      float a_[8], b_[8];
      *(float4*)&a_[0] = *(const float4*)&As[cur][k][ty * 8];
      *(float4*)&a_[4] = *(const float4*)&As[cur][k][ty * 8 + 4];
      *(float4*)&b_[0] = *(const float4*)&Bs[cur][k][bcol];
      *(float4*)&b_[4] = *(const float4*)&Bs[cur][k][bcol + 4];
#pragma unroll
      for (int i = 0; i < 8; ++i)
#pragma unroll
        for (int j = 0; j < 8; ++j) acc[i][j] += a_[i] * b_[j];
    }
  }

#pragma unroll
  for (int i = 0; i < 8; ++i) {
    const size_t m = (size_t)(m0 + ty * 8 + i);
#pragma unroll
    for (int j = 0; j < 8; j += 4) {
      float4 v;
      v.x = acc[i][j + 0] + bj[j0 + tx * 8 + j + 0];
      v.y = acc[i][j + 1] + bj[j0 + tx * 8 + j + 1];
      v.z = acc[i][j + 2] + bj[j0 + tx * 8 + j + 2];
      v.w = acc[i][j + 3] + bj[j0 + tx * 8 + j + 3];
      *(float4*)(C + m * J_ + j0 + tx * 8 + j) = v;
    }
  }
}

// ============================================================
// decode helpers — 16-way split protocol (r12 verbatim)
// ============================================================
__device__ __forceinline__ float sigmoidf_(float x) {
  return 1.f / (1.f + expf(-x));
}

__device__ __forceinline__ void flag_round16(int row, int tid, int& target) {
  target += 16;
  __syncthreads();  // all exchange stores issued/drained before flag
  if (tid == 0) {
    __hip_atomic_fetch_add(&g_flag[row], 1u, __ATOMIC_RELEASE,
                           __HIP_MEMORY_SCOPE_AGENT);
    while (__hip_atomic_load(&g_flag[row], __ATOMIC_ACQUIRE,
                             __HIP_MEMORY_SCOPE_AGENT) < (unsigned)target)
      __builtin_amdgcn_s_sleep(1);
  }
  __syncthreads();
}

// Recompute pending LSTM state + gproj from symbol s (28 = null).
// 2 flag rounds. 80 gate rows/block, 2 threads/row (k-range halves merged
// via shfl). c-state block-local (registers of threads 0..19).
__device__ void recompute16(
    int s, int row, int k16, int tid, int par, int& target,
    const float* __restrict__ wh0, const float* __restrict__ wi1,
    const float* __restrict__ wh1, const float* __restrict__ w_g,
    float* h0s, float* h1s, float* gates,
    float& c0, float& c1, float2& gp) {
  const int p = tid >> 1;             // gate-row index (valid < 80)
  const int half = tid & 1;
  const int g = p / HS16_;
  const int il = p - g * HS16_;
  const int o = g * H_ + k16 * HS16_ + il;
  const int k0 = half * (H_ / 2);     // 0 or 160

  // ---- layer 0 gates: Xi0[s][o] + wh0[o,:] @ h0_old (half-range each) ----
  if (p < 4 * HS16_) {
    const float* wr = wh0 + (size_t)o * H_;
    float acc = half ? 0.f : g_Xi0[s][o];
    for (int kk = k0; kk < k0 + H_ / 2; kk += 4) {
      float4 h4 = *(const float4*)&h0s[kk];
      float4 w4 = *(const float4*)&wr[kk];
      acc += h4.x * w4.x + h4.y * w4.y + h4.z * w4.z + h4.w * w4.w;
    }
    acc += __shfl_xor(acc, 1, 2);     // (Xi0 + lo-half) + hi-half on half==0
    if (half == 0) gates[p] = acc;
  }
  __syncthreads();
  if (tid < HS16_) {
    float ig = sigmoidf_(gates[tid]);
    float fg = sigmoidf_(gates[HS16_ + tid]);
    float gg = tanhf(gates[2 * HS16_ + tid]);
    float og = sigmoidf_(gates[3 * HS16_ + tid]);
    float c2 = fg * c0 + ig * gg;
    c0 = c2;
    float h2 = og * tanhf(c2);
    __hip_atomic_store(&g_h0x[par][row][k16 * HS16_ + tid], h2,
                       __ATOMIC_RELAXED, __HIP_MEMORY_SCOPE_AGENT);
  }
  // ---- overlap S1 wait with wh1 @ h1_old (half-range) ----
  float acc1 = 0.f;
  if (p < 4 * HS16_) {
    const float* whr = wh1 + (size_t)o * H_;
    acc1 = half ? 0.f : g_b1s[o];
    for (int kk = k0; kk < k0 + H_ / 2; kk += 4) {
      float4 h4 = *(const float4*)&h1s[kk];
      float4 w4 = *(const float4*)&whr[kk];
      acc1 += h4.x * w4.x + h4.y * w4.y + h4.z * w4.z + h4.w * w4.w;
    }
  }
  flag_round16(row, tid, target);   // S1: h0 slices ready
  h0s[tid] = __hip_atomic_load(&g_h0x[par][row][tid], __ATOMIC_RELAXED,
                               __HIP_MEMORY_SCOPE_AGENT);
  if (tid < H_ - 256)
    h0s[256 + tid] = __hip_atomic_load(&g_h0x[par][row][256 + tid],
                                       __ATOMIC_RELAXED, __HIP_MEMORY_SCOPE_AGENT);
  __syncthreads();
  // ---- layer1 gates += wi1[o,:] @ h0_new (half-range), merge halves ----
  if (p < 4 * HS16_) {
    const float* wir = wi1 + (size_t)o * H_;
    for (int kk = k0; kk < k0 + H_ / 2; kk += 4) {
      float4 x4 = *(const float4*)&h0s[kk];
      float4 w4 = *(const float4*)&wir[kk];
      acc1 += x4.x * w4.x + x4.y * w4.y + x4.z * w4.z + x4.w * w4.w;
    }
    acc1 += __shfl_xor(acc1, 1, 2);
    if (half == 0) gates[p] = acc1;
  }
  __syncthreads();
  if (tid < HS16_) {
    float ig = sigmoidf_(gates[tid]);
    float fg = sigmoidf_(gates[HS16_ + tid]);
    float gg = tanhf(gates[2 * HS16_ + tid]);
    float og = sigmoidf_(gates[3 * HS16_ + tid]);
    float c2 = fg * c1 + ig * gg;
    c1 = c2;
    float h2 = og * tanhf(c2);
    h1s[k16 * HS16_ + tid] = h2;
    __hip_atomic_store(&g_h1x[par][row][k16 * HS16_ + tid], h2,
                       __ATOMIC_RELAXED, __HIP_MEMORY_SCOPE_AGENT);
  }
  __syncthreads();
  // ---- gproj partials over own 20-wide h1 slice: j = tid, tid+256 ----
  {
    const float* hsl = &h1s[k16 * HS16_];
#pragma unroll
    for (int jj = 0; jj < 2; ++jj) {
      const int j = tid + jj * 256;
      const float* wgr = w_g + (size_t)j * H_ + k16 * HS16_;
      float a = 0.f;
#pragma unroll
      for (int kk = 0; kk < HS16_; kk += 4) {
        float4 h4 = *(const float4*)&hsl[kk];
        float4 w4 = *(const float4*)&wgr[kk];
        a += h4.x * w4.x + h4.y * w4.y + h4.z * w4.z + h4.w * w4.w;
      }
      __hip_atomic_store(&g_gpx[par][row][k16][j], a, __ATOMIC_RELAXED,
                         __HIP_MEMORY_SCOPE_AGENT);
    }
  }
  flag_round16(row, tid, target);   // S2: h1 slices + gp partials ready
  {
    float ax = 0.f, ay = 0.f;
#pragma unroll
    for (int kk = 0; kk < 16; ++kk) {
      ax += __hip_atomic_load(&g_gpx[par][row][kk][2 * tid], __ATOMIC_RELAXED,
                              __HIP_MEMORY_SCOPE_AGENT);
      ay += __hip_atomic_load(&g_gpx[par][row][kk][2 * tid + 1], __ATOMIC_RELAXED,
                              __HIP_MEMORY_SCOPE_AGENT);
    }
    gp.x = ax; gp.y = ay;
  }
  h1s[tid] = __hip_atomic_load(&g_h1x[par][row][tid], __ATOMIC_RELAXED,
                               __HIP_MEMORY_SCOPE_AGENT);
  if (tid < H_ - 256)
    h1s[256 + tid] = __hip_atomic_load(&g_h1x[par][row][256 + tid],
                                       __ATOMIC_RELAXED, __HIP_MEMORY_SCOPE_AGENT);
  __syncthreads();
}

// ============================================================
// Kernel 2: decode, 16 blocks/row x 256 threads (1024 blocks, 4/CU).
// w_o split: q=0..7 in registers (32 VGPR), q=8..15 in LDS (32 KB) ->
// per-thread live regs ~60 <= the allocator's 64 budget, no spill.
// ============================================================
__global__ __launch_bounds__(256, 4) void decode16(
    const float* __restrict__ Fproj, const int* __restrict__ f_lens,
    const float* __restrict__ wh0,
    const float* __restrict__ wi1, const float* __restrict__ wh1,
    const float* __restrict__ w_g,
    const float* __restrict__ w_o, const float* __restrict__ b_o,
    int* __restrict__ res, int* __restrict__ nsym) {
  const int bid = blockIdx.x;
  const int k16 = bid & 15;                      // slice -> XCD (bid%8 pins pairs)
  const int row = ((bid >> 4) + 4 * k16) & 63;   // scrambled co-residency
  const int tid = threadIdx.x;
  const int f_len = f_lens[row];

  __shared__ __align__(16) float h0s[H_], h1s[H_];
  __shared__ __align__(16) float gates[4 * HS16_];
  __shared__ __align__(16) float hjs[J_];
  __shared__ __align__(16) float woL[8][256][4];  // w_o q=8..15, own-slot reads
  __shared__ float logits[32];

  // blank-path: v = tid>>3 (vocab word), lq = tid&7; lane covers
  // j = lq*4 + 32*q + e (q<16, e<4); q=0..7 regs, q=8..15 LDS
  const int v = tid >> 3;
  const int lq = tid & 7;
  float4 wo[8];
  float bo = 0.f;
#pragma unroll
  for (int q = 0; q < 8; ++q) {
    float4 z = {0.f, 0.f, 0.f, 0.f};
    wo[q] = (v < V_) ? *(const float4*)(w_o + (size_t)v * J_ + lq * 4 + 32 * q) : z;
    *(float4*)&woL[q][tid][0] =
        (v < V_) ? *(const float4*)(w_o + (size_t)v * J_ + lq * 4 + 32 * (q + 8)) : z;
  }
  if (v < V_) bo = b_o[v];

  for (int i = tid; i < H_; i += 256) { h0s[i] = 0.f; h1s[i] = 0.f; }
  float c0 = 0.f, c1 = 0.f;
  float2 gp = {0.f, 0.f};
  int target = 0;
  __syncthreads();

  // initial pending state from (last=-1, h=0, c=0)
  recompute16(BLANK_, row, k16, tid, 0, target, wh0, wi1, wh1, w_g,
              h0s, h1s, gates, c0, c1, gp);
  int ecount = 1;

  int t_loc = 0, sym_add = 0, res_idx = -1;
  float2 fp = *(const float2*)(Fproj + (size_t)row * J_ + 2 * tid);  // t=0

  while (t_loc < f_len) {
    const int tn = (t_loc + 1 < T_) ? t_loc + 1 : T_ - 1;
    float2 fpn = *(const float2*)(Fproj + ((size_t)tn * N_ + row) * J_ + 2 * tid);

    float hx = fp.x + gp.x, hy = fp.y + gp.y;
    float2 hj2 = {hx > 0.f ? hx : 0.f, hy > 0.f ? hy : 0.f};
    *(float2*)&hjs[2 * tid] = hj2;
    __syncthreads();                    // B1

    float p = 0.f;
    if (v < V_) {
#pragma unroll
      for (int q = 0; q < 8; ++q) {
        float4 h4 = *(const float4*)&hjs[lq * 4 + 32 * q];
        p += h4.x * wo[q].x + h4.y * wo[q].y + h4.z * wo[q].z + h4.w * wo[q].w;
      }
#pragma unroll
      for (int q = 8; q < 16; ++q) {
        float4 h4 = *(const float4*)&hjs[lq * 4 + 32 * q];
        float4 w4 = *(const float4*)&woL[q - 8][tid][0];
        p += h4.x * w4.x + h4.y * w4.y + h4.z * w4.z + h4.w * w4.w;
      }
    }
    p += __shfl_xor(p, 4, 8);
    p += __shfl_xor(p, 2, 8);
    p += __shfl_xor(p, 1, 8);
    if (v < V_ && lq == 0) logits[v] = p + bo;
    __syncthreads();                    // B2

    // redundant argmax (first-max tie-break, identical everywhere)
    float best = logits[0];
    int bi = 0;
#pragma unroll
    for (int vv = 1; vv < V_; ++vv) {
      float lv = logits[vv];
      if (lv > best) { best = lv; bi = vv; }
    }
    const int emit = (bi != BLANK_) && (sym_add < MAXSYM_);

    if (emit) {
      res_idx += 1;
      if (k16 == 0 && tid == 0) res[(size_t)row * RESW_ + res_idx] = bi;
      sym_add += 1;
      recompute16(bi, row, k16, tid, ecount & 1, target, wh0, wi1, wh1, w_g,
                  h0s, h1s, gates, c0, c1, gp);
      ecount += 1;
    } else {
      sym_add = 0;
      t_loc += 1;
      fp = fpn;
    }
  }

  if (k16 == 0 && tid == 0) nsym[row] = res_idx + 1;
}

// ============================================================
extern "C" void kernel_launch(void* const* d_in, const int* in_sizes, int n_in,
                              void* d_out, int out_size, void* d_ws, size_t ws_size,
                              hipStream_t stream) {
  const float* f      = (const float*)d_in[0];
  const int*   f_lens = (const int*)d_in[1];
  const float* emb    = (const float*)d_in[2];
  const float* wi0    = (const float*)d_in[3];
  const float* wh0    = (const float*)d_in[4];
  const float* bi0    = (const float*)d_in[5];
  const float* bh0    = (const float*)d_in[6];
  const float* wi1    = (const float*)d_in[7];
  const float* wh1    = (const float*)d_in[8];
  const float* bi1    = (const float*)d_in[9];
  const float* bh1    = (const float*)d_in[10];
  const float* w_f    = (const float*)d_in[11];
  const float* w_g    = (const float*)d_in[12];
  const float* b_j    = (const float*)d_in[13];
  const float* w_o    = (const float*)d_in[14];
  const float* b_o    = (const float*)d_in[15];

  int* out  = (int*)d_out;
  int* res  = out;                       // (64, 15360)
  int* nsym = out + (size_t)N_ * RESW_;  // (64,)

  float* Fproj = (float*)d_ws;  // T*N*J*4 = 64 MiB

  gemm_init_kernel<<<GEMMB_ + 32, 256, 0, stream>>>(
      f, w_f, b_j, Fproj, emb, wi0, bi0, bh0, bi1, bh1, res);

  decode16<<<N_ * 16, 256, 0, stream>>>(Fproj, f_lens, wh0, wi1, wh1, w_g,
                                        w_o, b_o, res, nsym);
}

// Round 14
// 1786.351 us; speedup vs baseline: 1.2310x; 1.0282x over previous
//
#include <hip/hip_runtime.h>
#include <math.h>

#define T_ 512
#define N_ 64
#define E_ 1024
#define H_ 320
#define HS16_ 20          // H_/16 per-block h-slice
#define J_ 512
#define V_ 29
#define BLANK_ 28
#define MAXSYM_ 30
#define RESW_ (MAXSYM_ * T_)   // 15360

#define BM_ 128
#define BN_ 128
#define BK_ 16
#define GEMMB_ 1024       // GEMM blocks; aux (init) blocks appended after

// ---------------- static device memory ----------------
__device__ float g_Xi0[V_][4 * H_];      // wi0@emb[s]+bi0+bh0; row 28 = bias only
__device__ float g_b1s[4 * H_];          // bi1 + bh1
__device__ float g_h0x[2][N_][H_];       // exchange buffers (parity double-buffered)
__device__ float g_h1x[2][N_][H_];
__device__ float g_gpx[2][N_][16][J_];   // gproj partials per source block
__device__ unsigned int g_arr[N_][16][16];  // arrival flags, 64B-padded slots

// ============================================================
// Kernel 1: Fproj GEMM (double-buffered LDS, 1 barrier/K-tile)
// + (tail blocks) Xi0 / b1s / flags / res-fill.
// ============================================================
#define BSW_ 144   // 128 + 4*4 pad
__device__ __forceinline__ int padcol(int c) { return c + ((c >> 5) << 2); }

__global__ __launch_bounds__(256) void gemm_init_kernel(
    const float* __restrict__ A, const float* __restrict__ B,
    const float* __restrict__ bj, float* __restrict__ C,
    const float* __restrict__ emb, const float* __restrict__ wi0,
    const float* __restrict__ bi0, const float* __restrict__ bh0,
    const float* __restrict__ bi1, const float* __restrict__ bh1,
    int* __restrict__ res) {
  const int bid = blockIdx.x;
  const int tid = threadIdx.x;

  if (bid >= GEMMB_) {
    const int ab = bid - GEMMB_;   // 0..31
    if (ab < V_) {
      // ---- Xi0 row ab (28 = null input) + b1s ----
      __shared__ __align__(16) float xs[H_];
      for (int i = tid; i < H_; i += 256)
        xs[i] = (ab < V_ - 1) ? emb[(size_t)ab * H_ + i] : 0.f;
      __syncthreads();
      for (int o = tid; o < 4 * H_; o += 256) {
        float acc = bi0[o] + bh0[o];
        if (ab < V_ - 1) {
          const float* wr = wi0 + (size_t)o * H_;
          for (int k = 0; k < H_; k += 4) {
            float4 x4 = *(const float4*)&xs[k];
            float4 w4 = *(const float4*)&wr[k];
            acc += x4.x * w4.x + x4.y * w4.y + x4.z * w4.z + x4.w * w4.w;
          }
        }
        g_Xi0[ab][o] = acc;
        if (ab == 0) g_b1s[o] = bi1[o] + bh1[o];
      }
    } else {
      // ---- 3 blocks: arrival-flag reset + res fill (int4) ----
      if (ab == V_) {
        for (int i = tid; i < N_ * 16 * 16; i += 256)
          ((unsigned int*)g_arr)[i] = 0u;
      }
      const int fb = ab - V_;             // 0..2
      int4* r4 = (int4*)res;
      const size_t tot = (size_t)N_ * RESW_ / 4;
      const size_t i0 = (size_t)fb * 256 + tid;
      const int4 mval = {-1, -1, -1, -1};
      for (size_t i = i0; i < tot; i += 3 * 256) r4[i] = mval;
    }
    return;
  }

  // ---------------- GEMM (double-buffered) ----------------
  __shared__ __align__(16) float As[2][BK_][BM_ + 4];
  __shared__ __align__(16) float Bs[2][BK_][BSW_];
  const int m0 = blockIdx.x / 4 * BM_;
  const int j0 = (blockIdx.x & 3) * BN_;
  const int tx = tid & 15, ty = tid >> 4;
  const int sm = tid >> 1;
  const int sk = (tid & 1) << 3;
  const int smP = padcol(sm);
  const int bcol = padcol(tx * 8);   // tx*8 and tx*8+4 share a 32-block

  float acc[8][8];
#pragma unroll
  for (int i = 0; i < 8; ++i)
#pragma unroll
    for (int j = 0; j < 8; ++j) acc[i][j] = 0.f;

  const float* arow = A + (size_t)(m0 + sm) * E_ + sk;
  const float* brow = B + (size_t)(j0 + sm) * E_ + sk;

  // preload K-tile 0
  float4 av0 = *(const float4*)(arow + 0);
  float4 av1 = *(const float4*)(arow + 4);
  float4 bv0 = *(const float4*)(brow + 0);
  float4 bv1 = *(const float4*)(brow + 4);

  const int NIT = E_ / BK_;  // 64
  for (int it = 0; it < NIT; ++it) {
    const int cur = it & 1;
    // store staged regs -> LDS[cur]
    As[cur][sk + 0][sm] = av0.x; As[cur][sk + 1][sm] = av0.y;
    As[cur][sk + 2][sm] = av0.z; As[cur][sk + 3][sm] = av0.w;
    As[cur][sk + 4][sm] = av1.x; As[cur][sk + 5][sm] = av1.y;
    As[cur][sk + 6][sm] = av1.z; As[cur][sk + 7][sm] = av1.w;
    Bs[cur][sk + 0][smP] = bv0.x; Bs[cur][sk + 1][smP] = bv0.y;
    Bs[cur][sk + 2][smP] = bv0.z; Bs[cur][sk + 3][smP] = bv0.w;
    Bs[cur][sk + 4][smP] = bv1.x; Bs[cur][sk + 5][smP] = bv1.y;
    Bs[cur][sk + 6][smP] = bv1.z; Bs[cur][sk + 7][smP] = bv1.w;
    __syncthreads();   // single barrier: separates it-1 reads from it+1 writes
    // issue next tile's global loads (latency hides under compute)
    if (it + 1 < NIT) {
      const int kc = (it + 1) * BK_;
      av0 = *(const float4*)(arow + kc);
      av1 = *(const float4*)(arow + kc + 4);
      bv0 = *(const float4*)(brow + kc);
      bv1 = *(const float4*)(brow + kc + 4);
    }
    // compute from LDS[cur]
#pragma unroll
    for (int k = 0; k < BK_; ++k) {
      float a_[8], b_[8];
      *(float4*)&a_[0] = *(const float4*)&As[cur][k][ty * 8];
      *(float4*)&a_[4] = *(const float4*)&As[cur][k][ty * 8 + 4];
      *(float4*)&b_[0] = *(const float4*)&Bs[cur][k][bcol];
      *(float4*)&b_[4] = *(const float4*)&Bs[cur][k][bcol + 4];
#pragma unroll
      for (int i = 0; i < 8; ++i)
#pragma unroll
        for (int j = 0; j < 8; ++j) acc[i][j] += a_[i] * b_[j];
    }
  }

#pragma unroll
  for (int i = 0; i < 8; ++i) {
    const size_t m = (size_t)(m0 + ty * 8 + i);
#pragma unroll
    for (int j = 0; j < 8; j += 4) {
      float4 v;
      v.x = acc[i][j + 0] + bj[j0 + tx * 8 + j + 0];
      v.y = acc[i][j + 1] + bj[j0 + tx * 8 + j + 1];
      v.z = acc[i][j + 2] + bj[j0 + tx * 8 + j + 2];
      v.w = acc[i][j + 3] + bj[j0 + tx * 8 + j + 3];
      *(float4*)(C + m * J_ + j0 + tx * 8 + j) = v;
    }
  }
}

// ============================================================
// decode helpers — 16-way split, arrival-flag sync (no atomic RMW)
// ============================================================
__device__ __forceinline__ float sigmoidf_(float x) {
  return 1.f / (1.f + expf(-x));
}

// One sync round: each block RELEASE-stores its round number to its own
// 64B-padded slot; lanes 0..15 ACQUIRE-poll the 16 slots in parallel.
__device__ __forceinline__ void flag_round16(int row, int k16, int tid,
                                             int& seq) {
  seq += 1;
  __syncthreads();  // all exchange stores issued/drained before flag
  if (tid == 0)
    __hip_atomic_store(&g_arr[row][k16][0], (unsigned)seq, __ATOMIC_RELEASE,
                       __HIP_MEMORY_SCOPE_AGENT);
  if (tid < 16) {
    while (__hip_atomic_load(&g_arr[row][tid][0], __ATOMIC_ACQUIRE,
                             __HIP_MEMORY_SCOPE_AGENT) < (unsigned)seq)
      __builtin_amdgcn_s_sleep(1);
  }
  __syncthreads();
}

// Recompute pending LSTM state + gproj from symbol s (28 = null).
// 2 flag rounds. 80 gate rows/block, 2 threads/row (k-range halves merged
// via shfl). c-state block-local (registers of threads 0..19).
__device__ void recompute16(
    int s, int row, int k16, int tid, int par, int& seq,
    const float* __restrict__ wh0, const float* __restrict__ wi1,
    const float* __restrict__ wh1, const float* __restrict__ w_g,
    float* h0s, float* h1s, float* gates,
    float& c0, float& c1, float2& gp) {
  const int p = tid >> 1;             // gate-row index (valid < 80)
  const int half = tid & 1;
  const int g = p / HS16_;
  const int il = p - g * HS16_;
  const int o = g * H_ + k16 * HS16_ + il;
  const int k0 = half * (H_ / 2);     // 0 or 160

  // ---- layer 0 gates: Xi0[s][o] + wh0[o,:] @ h0_old (half-range each) ----
  if (p < 4 * HS16_) {
    const float* wr = wh0 + (size_t)o * H_;
    float acc = half ? 0.f : g_Xi0[s][o];
    for (int kk = k0; kk < k0 + H_ / 2; kk += 4) {
      float4 h4 = *(const float4*)&h0s[kk];
      float4 w4 = *(const float4*)&wr[kk];
      acc += h4.x * w4.x + h4.y * w4.y + h4.z * w4.z + h4.w * w4.w;
    }
    acc += __shfl_xor(acc, 1, 2);     // (Xi0 + lo-half) + hi-half on half==0
    if (half == 0) gates[p] = acc;
  }
  __syncthreads();
  if (tid < HS16_) {
    float ig = sigmoidf_(gates[tid]);
    float fg = sigmoidf_(gates[HS16_ + tid]);
    float gg = tanhf(gates[2 * HS16_ + tid]);
    float og = sigmoidf_(gates[3 * HS16_ + tid]);
    float c2 = fg * c0 + ig * gg;
    c0 = c2;
    float h2 = og * tanhf(c2);
    __hip_atomic_store(&g_h0x[par][row][k16 * HS16_ + tid], h2,
                       __ATOMIC_RELAXED, __HIP_MEMORY_SCOPE_AGENT);
  }
  // ---- overlap S1 wait with wh1 @ h1_old (half-range) ----
  float acc1 = 0.f;
  if (p < 4 * HS16_) {
    const float* whr = wh1 + (size_t)o * H_;
    acc1 = half ? 0.f : g_b1s[o];
    for (int kk = k0; kk < k0 + H_ / 2; kk += 4) {
      float4 h4 = *(const float4*)&h1s[kk];
      float4 w4 = *(const float4*)&whr[kk];
      acc1 += h4.x * w4.x + h4.y * w4.y + h4.z * w4.z + h4.w * w4.w;
    }
  }
  flag_round16(row, k16, tid, seq);   // S1: h0 slices ready
  h0s[tid] = __hip_atomic_load(&g_h0x[par][row][tid], __ATOMIC_RELAXED,
                               __HIP_MEMORY_SCOPE_AGENT);
  if (tid < H_ - 256)
    h0s[256 + tid] = __hip_atomic_load(&g_h0x[par][row][256 + tid],
                                       __ATOMIC_RELAXED, __HIP_MEMORY_SCOPE_AGENT);
  __syncthreads();
  // ---- layer1 gates += wi1[o,:] @ h0_new (half-range), merge halves ----
  if (p < 4 * HS16_) {
    const float* wir = wi1 + (size_t)o * H_;
    for (int kk = k0; kk < k0 + H_ / 2; kk += 4) {
      float4 x4 = *(const float4*)&h0s[kk];
      float4 w4 = *(const float4*)&wir[kk];
      acc1 += x4.x * w4.x + x4.y * w4.y + x4.z * w4.z + x4.w * w4.w;
    }
    acc1 += __shfl_xor(acc1, 1, 2);
    if (half == 0) gates[p] = acc1;
  }
  __syncthreads();
  if (tid < HS16_) {
    float ig = sigmoidf_(gates[tid]);
    float fg = sigmoidf_(gates[HS16_ + tid]);
    float gg = tanhf(gates[2 * HS16_ + tid]);
    float og = sigmoidf_(gates[3 * HS16_ + tid]);
    float c2 = fg * c1 + ig * gg;
    c1 = c2;
    float h2 = og * tanhf(c2);
    h1s[k16 * HS16_ + tid] = h2;
    __hip_atomic_store(&g_h1x[par][row][k16 * HS16_ + tid], h2,
                       __ATOMIC_RELAXED, __HIP_MEMORY_SCOPE_AGENT);
  }
  __syncthreads();
  // ---- gproj partials over own 20-wide h1 slice: j = tid, tid+256 ----
  {
    const float* hsl = &h1s[k16 * HS16_];
#pragma unroll
    for (int jj = 0; jj < 2; ++jj) {
      const int j = tid + jj * 256;
      const float* wgr = w_g + (size_t)j * H_ + k16 * HS16_;
      float a = 0.f;
#pragma unroll
      for (int kk = 0; kk < HS16_; kk += 4) {
        float4 h4 = *(const float4*)&hsl[kk];
        float4 w4 = *(const float4*)&wgr[kk];
        a += h4.x * w4.x + h4.y * w4.y + h4.z * w4.z + h4.w * w4.w;
      }
      __hip_atomic_store(&g_gpx[par][row][k16][j], a, __ATOMIC_RELAXED,
                         __HIP_MEMORY_SCOPE_AGENT);
    }
  }
  flag_round16(row, k16, tid, seq);   // S2: h1 slices + gp partials ready
  {
    float ax = 0.f, ay = 0.f;
#pragma unroll
    for (int kk = 0; kk < 16; ++kk) {
      ax += __hip_atomic_load(&g_gpx[par][row][kk][2 * tid], __ATOMIC_RELAXED,
                              __HIP_MEMORY_SCOPE_AGENT);
      ay += __hip_atomic_load(&g_gpx[par][row][kk][2 * tid + 1], __ATOMIC_RELAXED,
                              __HIP_MEMORY_SCOPE_AGENT);
    }
    gp.x = ax; gp.y = ay;
  }
  h1s[tid] = __hip_atomic_load(&g_h1x[par][row][tid], __ATOMIC_RELAXED,
                               __HIP_MEMORY_SCOPE_AGENT);
  if (tid < H_ - 256)
    h1s[256 + tid] = __hip_atomic_load(&g_h1x[par][row][256 + tid],
                                       __ATOMIC_RELAXED, __HIP_MEMORY_SCOPE_AGENT);
  __syncthreads();
}

// ============================================================
// Kernel 2: decode, 16 blocks/row x 256 threads (1024 blocks, 4/CU).
// w_o split: q=0..7 in registers (32 VGPR), q=8..15 in LDS (32 KB) ->
// per-thread live regs ~60 <= the allocator's 64 budget, no spill.
// ============================================================
__global__ __launch_bounds__(256, 4) void decode16(
    const float* __restrict__ Fproj, const int* __restrict__ f_lens,
    const float* __restrict__ wh0,
    const float* __restrict__ wi1, const float* __restrict__ wh1,
    const float* __restrict__ w_g,
    const float* __restrict__ w_o, const float* __restrict__ b_o,
    int* __restrict__ res, int* __restrict__ nsym) {
  const int bid = blockIdx.x;
  const int k16 = bid & 15;                      // slice -> XCD (bid%8 pins pairs)
  const int row = ((bid >> 4) + 4 * k16) & 63;   // scrambled co-residency
  const int tid = threadIdx.x;
  const int f_len = f_lens[row];

  __shared__ __align__(16) float h0s[H_], h1s[H_];
  __shared__ __align__(16) float gates[4 * HS16_];
  __shared__ __align__(16) float hjs[J_];
  __shared__ __align__(16) float woL[8][256][4];  // w_o q=8..15, own-slot reads
  __shared__ float logits[32];

  // blank-path: v = tid>>3 (vocab word), lq = tid&7; lane covers
  // j = lq*4 + 32*q + e (q<16, e<4); q=0..7 regs, q=8..15 LDS
  const int v = tid >> 3;
  const int lq = tid & 7;
  float4 wo[8];
  float bo = 0.f;
#pragma unroll
  for (int q = 0; q < 8; ++q) {
    float4 z = {0.f, 0.f, 0.f, 0.f};
    wo[q] = (v < V_) ? *(const float4*)(w_o + (size_t)v * J_ + lq * 4 + 32 * q) : z;
    *(float4*)&woL[q][tid][0] =
        (v < V_) ? *(const float4*)(w_o + (size_t)v * J_ + lq * 4 + 32 * (q + 8)) : z;
  }
  if (v < V_) bo = b_o[v];

  for (int i = tid; i < H_; i += 256) { h0s[i] = 0.f; h1s[i] = 0.f; }
  float c0 = 0.f, c1 = 0.f;
  float2 gp = {0.f, 0.f};
  int seq = 0;
  __syncthreads();

  // initial pending state from (last=-1, h=0, c=0)
  recompute16(BLANK_, row, k16, tid, 0, seq, wh0, wi1, wh1, w_g,
              h0s, h1s, gates, c0, c1, gp);
  int ecount = 1;

  int t_loc = 0, sym_add = 0, res_idx = -1;
  float2 fp = *(const float2*)(Fproj + (size_t)row * J_ + 2 * tid);  // t=0

  while (t_loc < f_len) {
    const int tn = (t_loc + 1 < T_) ? t_loc + 1 : T_ - 1;
    float2 fpn = *(const float2*)(Fproj + ((size_t)tn * N_ + row) * J_ + 2 * tid);

    float hx = fp.x + gp.x, hy = fp.y + gp.y;
    float2 hj2 = {hx > 0.f ? hx : 0.f, hy > 0.f ? hy : 0.f};
    *(float2*)&hjs[2 * tid] = hj2;
    __syncthreads();                    // B1

    float p = 0.f;
    if (v < V_) {
#pragma unroll
      for (int q = 0; q < 8; ++q) {
        float4 h4 = *(const float4*)&hjs[lq * 4 + 32 * q];
        p += h4.x * wo[q].x + h4.y * wo[q].y + h4.z * wo[q].z + h4.w * wo[q].w;
      }
#pragma unroll
      for (int q = 8; q < 16; ++q) {
        float4 h4 = *(const float4*)&hjs[lq * 4 + 32 * q];
        float4 w4 = *(const float4*)&woL[q - 8][tid][0];
        p += h4.x * w4.x + h4.y * w4.y + h4.z * w4.z + h4.w * w4.w;
      }
    }
    p += __shfl_xor(p, 4, 8);
    p += __shfl_xor(p, 2, 8);
    p += __shfl_xor(p, 1, 8);
    if (v < V_ && lq == 0) logits[v] = p + bo;
    __syncthreads();                    // B2

    // redundant argmax (first-max tie-break, identical everywhere)
    float best = logits[0];
    int bi = 0;
#pragma unroll
    for (int vv = 1; vv < V_; ++vv) {
      float lv = logits[vv];
      if (lv > best) { best = lv; bi = vv; }
    }
    const int emit = (bi != BLANK_) && (sym_add < MAXSYM_);

    if (emit) {
      res_idx += 1;
      if (k16 == 0 && tid == 0) res[(size_t)row * RESW_ + res_idx] = bi;
      sym_add += 1;
      recompute16(bi, row, k16, tid, ecount & 1, seq, wh0, wi1, wh1, w_g,
                  h0s, h1s, gates, c0, c1, gp);
      ecount += 1;
    } else {
      sym_add = 0;
      t_loc += 1;
      fp = fpn;
    }
  }

  if (k16 == 0 && tid == 0) nsym[row] = res_idx + 1;
}

// ============================================================
extern "C" void kernel_launch(void* const* d_in, const int* in_sizes, int n_in,
                              void* d_out, int out_size, void* d_ws, size_t ws_size,
                              hipStream_t stream) {
  const float* f      = (const float*)d_in[0];
  const int*   f_lens = (const int*)d_in[1];
  const float* emb    = (const float*)d_in[2];
  const float* wi0    = (const float*)d_in[3];
  const float* wh0    = (const float*)d_in[4];
  const float* bi0    = (const float*)d_in[5];
  const float* bh0    = (const float*)d_in[6];
  const float* wi1    = (const float*)d_in[7];
  const float* wh1    = (const float*)d_in[8];
  const float* bi1    = (const float*)d_in[9];
  const float* bh1    = (const float*)d_in[10];
  const float* w_f    = (const float*)d_in[11];
  const float* w_g    = (const float*)d_in[12];
  const float* b_j    = (const float*)d_in[13];
  const float* w_o    = (const float*)d_in[14];
  const float* b_o    = (const float*)d_in[15];

  int* out  = (int*)d_out;
  int* res  = out;                       // (64, 15360)
  int* nsym = out + (size_t)N_ * RESW_;  // (64,)

  float* Fproj = (float*)d_ws;  // T*N*J*4 = 64 MiB

  gemm_init_kernel<<<GEMMB_ + 32, 256, 0, stream>>>(
      f, w_f, b_j, Fproj, emb, wi0, bi0, bh0, bi1, bh1, res);

  decode16<<<N_ * 16, 256, 0, stream>>>(Fproj, f_lens, wh0, wi1, wh1, w_g,
                                        w_o, b_o, res, nsym);
}